// Round 11
// baseline (172.102 us; speedup 1.0000x reference)
//
#include <hip/hip_runtime.h>
#include <hip/hip_bf16.h>

typedef __attribute__((ext_vector_type(8))) short short8;
typedef __attribute__((ext_vector_type(4))) float f32x4;

// Problem constants (from reference)
constexpr int NN = 50000;   // nodes
constexpr int NE = 800000;  // edges
constexpr int FN = 64;      // node feat
constexpr int FE = 32;      // edge feat
constexpr int FG = 32;      // global feat
constexpr int OD = 64;      // out dim
constexpr int NG = 256;     // graphs

constexpr int SCAN_B = 256;
constexpr int NBLK = (NN + SCAN_B - 1) / SCAN_B;        // 196

constexpr int SLOTS_MAX = NE + 15 * NN;                 // 1.55M padded slots
constexpr int NWIN_MAX  = SLOTS_MAX / 16;               // 96875

constexpr int XCVT_BLOCKS = (NN * FN / 8 + 255) / 256;  // 1563
constexpr int PRE_BLOCKS  = XCVT_BLOCKS + (NG * 64) / 256;

constexpr int AGG4_BLOCKS = 512;                        // 2 blocks/CU (64 KB LDS each)
constexpr int AGG4_WAVES  = AGG4_BLOCKS * 4;            // 2048 waves
constexpr int NWIN_N = NN / 16;                         // 3125
constexpr int NODE_BLOCKS = 782;
constexpr int NODE_WAVES  = NODE_BLOCKS * 4;

static __device__ __forceinline__ unsigned pack_bf16(float a, float b) {
    __hip_bfloat162 h = __float22bfloat162_rn(float2{a, b});
    return *reinterpret_cast<unsigned*>(&h);
}

// Direct global->LDS 16 B load: no VGPR destination, so dozens can be in
// flight per wave. LDS dest is wave-uniform base + lane*16 (linear); the
// swizzle is folded into the per-lane GLOBAL source address (rule #21).
static __device__ __forceinline__ void gl16(const void* gsrc, void* ldst) {
    __builtin_amdgcn_global_load_lds(
        (const __attribute__((address_space(1))) void*)gsrc,
        (__attribute__((address_space(3))) void*)ldst, 16, 0, 0);
}

// ---------------------------------------------------------------------------
// Fused precompute: x->bf16 table, uW2b = b2 + u@W2_u (exact f32), zero cnt.
// ---------------------------------------------------------------------------
__global__ __launch_bounds__(256) void k_pre(const float* __restrict__ x,
                                             unsigned* __restrict__ xb32,
                                             const float* __restrict__ u,
                                             const float* __restrict__ W2,
                                             const float* __restrict__ b2,
                                             float* __restrict__ uW2b,
                                             int* __restrict__ cnt) {
    if (blockIdx.x >= XCVT_BLOCKS) {  // uW2b part
        const int lane = threadIdx.x & 63;
        float wcol[FG];
#pragma unroll
        for (int k = 0; k < FG; ++k) wcol[k] = W2[(FN + OD + k) * OD + lane];
        const float bias = b2[lane];
        int g = ((blockIdx.x - XCVT_BLOCKS) * 256 + threadIdx.x) >> 6;
        g = __builtin_amdgcn_readfirstlane(g);
        if (g >= NG) return;
        const float* __restrict__ urow = u + (size_t)g * FG;
        float acc = bias;
#pragma unroll
        for (int k = 0; k < FG; ++k) acc = fmaf(urow[k], wcol[k], acc);
        uW2b[(size_t)g * OD + lane] = acc;
        return;
    }
    const int i = blockIdx.x * 256 + threadIdx.x;
    if (i < NN) cnt[i] = 0;
    if (i >= NN * FN / 8) return;
    const float4* p = (const float4*)(x + (size_t)i * 8);
    float4 f0 = p[0], f1 = p[1];
    uint4 o;
    o.x = pack_bf16(f0.x, f0.y);
    o.y = pack_bf16(f0.z, f0.w);
    o.z = pack_bf16(f1.x, f1.y);
    o.w = pack_bf16(f1.z, f1.w);
    ((uint4*)xb32)[i] = o;
}

// ---------------------------------------------------------------------------
// Histogram of dst.
// ---------------------------------------------------------------------------
__global__ __launch_bounds__(256) void k_hist(const int* __restrict__ ei,
                                              int* __restrict__ cnt) {
    const int e = blockIdx.x * blockDim.x + threadIdx.x;
    if (e < NE) atomicAdd(&cnt[ei[e]], 1);
}

// ---------------------------------------------------------------------------
// Scan step 1 over PADDED counts (ceil16).
// ---------------------------------------------------------------------------
__global__ __launch_bounds__(SCAN_B) void k_scan1(const int* __restrict__ cnt,
                                                  int* __restrict__ pstart,
                                                  int* __restrict__ bsum) {
    __shared__ int lds[SCAN_B];
    const int i = blockIdx.x * SCAN_B + threadIdx.x;
    const int v = (i < NN) ? (((cnt[i] + 15) >> 4) << 4) : 0;
    lds[threadIdx.x] = v;
    __syncthreads();
#pragma unroll
    for (int off = 1; off < SCAN_B; off <<= 1) {
        int t = (threadIdx.x >= off) ? lds[threadIdx.x - off] : 0;
        __syncthreads();
        lds[threadIdx.x] += t;
        __syncthreads();
    }
    const int incl = lds[threadIdx.x];
    if (i < NN) pstart[i] = incl - v;
    if (threadIdx.x == SCAN_B - 1) bsum[blockIdx.x] = incl;
}

// ---------------------------------------------------------------------------
// Scan steps 2+3 fused + per-window segment ends (winend).
// ---------------------------------------------------------------------------
__global__ __launch_bounds__(SCAN_B) void k_scan23(int* __restrict__ pstart,
                                                   const int* __restrict__ bsum,
                                                   const int* __restrict__ cnt,
                                                   int* __restrict__ cursor,
                                                   int* __restrict__ winend) {
    __shared__ int lds[SCAN_B];
    const int t = threadIdx.x;
    lds[t] = (t < NBLK) ? bsum[t] : 0;
    __syncthreads();
#pragma unroll
    for (int off = 1; off < SCAN_B; off <<= 1) {
        int tv = (t >= off) ? lds[t - off] : 0;
        __syncthreads();
        lds[t] += tv;
        __syncthreads();
    }
    const int boff = (blockIdx.x == 0) ? 0 : lds[blockIdx.x - 1];

    const int i = blockIdx.x * SCAN_B + t;
    if (i < NN) {
        const int cn = cnt[i];
        const int pc = ((cn + 15) >> 4) << 4;
        const int s = pstart[i] + boff;
        pstart[i] = s;
        cursor[i] = s;
        const int end = s + cn;
        const int w0 = s >> 4;
        const int w1 = (s + pc) >> 4;
        for (int w = w0; w < w1; ++w) winend[w] = end;
        if (i == NN - 1) pstart[NN] = s + pc;
    }
}

// ---------------------------------------------------------------------------
// Light scatter: {src, e} int2 (8 B) into padded dst-sorted slots. Pads are
// left uninitialized — the agg kernel clamps garbage ids and masks rows.
// ---------------------------------------------------------------------------
__global__ __launch_bounds__(256) void k_scatter(const int* __restrict__ ei,
                                                 int* __restrict__ cursor,
                                                 int2* __restrict__ bucket) {
    const int e = blockIdx.x * blockDim.x + threadIdx.x;
    if (e < NE) {
        const int dst = ei[e];
        const int src = ei[NE + e];
        const int pos = atomicAdd(&cursor[dst], 1);
        bucket[pos] = make_int2(src, e);
    }
}

// ---------------------------------------------------------------------------
// Window MFMA with global_load_lds ring pipeline (the outstanding-miss fix):
//  - wave owns a contiguous chunk of windows; LDS ring of 4 slots x 4 KB
//    (16 ea rows f32 = 2 KB + 16 xb rows bf16 = 2 KB per window).
//  - per window, FOUR gl16x64-lane instructions fetch everything direct to
//    LDS (no VGPR): ~32 HBM lines in flight per window, 3 windows deep.
//  - s_waitcnt vmcnt(12): 12 newer gloads always exist (windows w+1..w+3),
//    vmcnt drains in order => gl(w) complete. sched_barrier(0) keeps the
//    compiler from hoisting ds_reads above the wait / gl-issues above reads.
//  - XOR swizzle (chunk m ^ (edge j & 7)) folded into per-lane GLOBAL source;
//    LDS linear; ds_read_b128 at c*128 stride then hits 8 lanes/bank-group
//    (the b128 optimum) instead of 16.
//  - bucket {src,e} and winend prefetched in ring-of-3 GROUP loads (4 windows
//    per group, one per-lane load) so no dependent wait drains the pipeline.
// Fragment layouts (mfma_f32_16x16x32_bf16), verified rounds 2-9:
//   A: row = lane&15, k = 8*(lane>>4)+i ; B: col = lane&15, same k
//   C: col = lane&15, row = (lane>>4)*4 + q
// ---------------------------------------------------------------------------
__global__ __launch_bounds__(256, 2) void k_aggw4(const int2* __restrict__ bucket,
                                                  const float* __restrict__ ea,
                                                  const unsigned short* __restrict__ xb,
                                                  const float* __restrict__ W1,
                                                  const float* __restrict__ b1,
                                                  const int* __restrict__ pstart,
                                                  const int* __restrict__ winend,
                                                  unsigned* __restrict__ partial32) {
    __shared__ char ldsbuf[65536];  // 4 waves x 4 slots x 4 KB
    const int l = threadIdx.x & 63;
    const int g = l >> 4;
    const int c = l & 15;

    // W1 B-fragments: wf[t][b] covers k = 32t.., cols 16b..16b+15
    short8 wf[3][4];
#pragma unroll
    for (int t = 0; t < 3; ++t)
#pragma unroll
        for (int b = 0; b < 4; ++b)
#pragma unroll
            for (int i = 0; i < 8; i += 2) {
                const int k = 32 * t + 8 * g + i;
                const unsigned p = pack_bf16(W1[k * OD + (c + 16 * b)],
                                             W1[(k + 1) * OD + (c + 16 * b)]);
                ((unsigned*)&wf[t][b])[i / 2] = p;
            }
    float bias[4];
#pragma unroll
    for (int b = 0; b < 4; ++b) bias[b] = b1[c + 16 * b];

    const int nwin = pstart[NN] >> 4;
    int wid = (blockIdx.x * blockDim.x + threadIdx.x) >> 6;
    wid = __builtin_amdgcn_readfirstlane(wid);
    const int chunk = (nwin + AGG4_WAVES - 1) / AGG4_WAVES;
    const int c0 = wid * chunk;
    int len = nwin - c0;
    if (len > chunk) len = chunk;
    if (len <= 0) return;

    char* myl = &ldsbuf[((threadIdx.x >> 6) & 3) * 16384];  // wave-uniform
    const int swz = (((l & 7) ^ ((l >> 3) & 7)) << 4);      // source swizzle

    // group loads: 4 windows per group, one per-lane entry (clamped)
    auto ldSE = [&](int G) -> int2 {
        int wr = 4 * G + (l >> 4);
        if (wr > len - 1) wr = len - 1;
        return bucket[(size_t)(c0 + wr) * 16 + (l & 15)];
    };
    auto ldEND = [&](int G) -> int {
        int wr = 4 * G + (l & 3);
        if (wr > len - 1) wr = len - 1;
        return winend[c0 + wr];
    };

    // issue one window's 4 gloads from quadrant qd of seH into ring slot p
    auto issue = [&](int2 seH, int qd, int p) {
        char* dst = myl + p * 4096;
#pragma unroll
        for (int half = 0; half < 2; ++half) {
            const int srcLane = (qd << 4) + (half << 3) + (l >> 3);
            int sv = __shfl(seH.x, srcLane);
            int ev = __shfl(seH.y, srcLane);
            sv = ((unsigned)sv < (unsigned)NN) ? sv : 0;  // pads are garbage:
            ev = ((unsigned)ev < (unsigned)NE) ? ev : 0;  // clamp, rows masked
            gl16((const char*)ea + ((size_t)ev * 128 + swz), dst + half * 1024);
            gl16((const char*)xb + ((size_t)sv * 128 + swz), dst + 2048 + half * 1024);
        }
    };

    // prologue: scalar prefetch rings, then fill the 4 LDS slots
    int2 se0 = ldSE(0);
    int2 seH = ldSE(1), seM = ldSE(2), seP = ldSE(3);
    int enH = ldEND(0), enM = ldEND(1), enP = ldEND(2);
#pragma unroll
    for (int i = 0; i < 4; ++i) {
        int wr = (i > len - 1) ? (len - 1) : i;
        issue(se0, wr, i);
    }

    for (int i = 0; i < len; ++i) {
        const int p = i & 3;
        const int w = c0 + i;

        // gl(w) complete once <=12 outstanding (12 newer gloads always exist)
        asm volatile("s_waitcnt vmcnt(12)" ::: "memory");
        __builtin_amdgcn_sched_barrier(0);

        const char* base = myl + p * 4096;
        const float4 e0 = *(const float4*)(base + c * 128 + (((2 * g) ^ (c & 7)) << 4));
        const float4 e1 = *(const float4*)(base + c * 128 + (((2 * g + 1) ^ (c & 7)) << 4));
        const uint4  x0 = *(const uint4*)(base + 2048 + c * 128 + ((g ^ (c & 7)) << 4));
        const uint4  x1 = *(const uint4*)(base + 2048 + c * 128 + (((g + 4) ^ (c & 7)) << 4));
        const int end = __shfl(enH, p);

        __builtin_amdgcn_sched_barrier(0);
        // refill slot p with window i+4 (clamped; redundant at tail is fine)
        {
            int wn = i + 4;
            if (wn > len - 1) wn = len - 1;
            int qd = wn - 4 * ((i >> 2) + 1);
            qd = qd < 0 ? 0 : (qd > 3 ? 3 : qd);
            issue(seH, qd, p);
        }
        if (p == 3) {  // group-end ring rotation (2 groups of lead time)
            seH = seM; seM = seP; seP = ldSE((i >> 2) + 4);
            enH = enM; enM = enP; enP = ldEND((i >> 2) + 3);
        }

        // compute window w
        const short8 a0 = *(const short8*)&x0;
        const short8 a1 = *(const short8*)&x1;
        uint4 q2;
        q2.x = pack_bf16(e0.x, e0.y);
        q2.y = pack_bf16(e0.z, e0.w);
        q2.z = pack_bf16(e1.x, e1.y);
        q2.w = pack_bf16(e1.z, e1.w);
        const short8 a2 = *(const short8*)&q2;

        float sv4[4];
#pragma unroll
        for (int b = 0; b < 4; ++b) {
            f32x4 acc = {0.f, 0.f, 0.f, 0.f};
            acc = __builtin_amdgcn_mfma_f32_16x16x32_bf16(a0, wf[0][b], acc, 0, 0, 0);
            acc = __builtin_amdgcn_mfma_f32_16x16x32_bf16(a1, wf[1][b], acc, 0, 0, 0);
            acc = __builtin_amdgcn_mfma_f32_16x16x32_bf16(a2, wf[2][b], acc, 0, 0, 0);
            float s = 0.0f;
#pragma unroll
            for (int q = 0; q < 4; ++q) {
                const int row = w * 16 + 4 * g + q;
                const float v = fmaxf(acc[q] + bias[b], 0.0f);
                s += (row < end) ? v : 0.0f;
            }
            s += __shfl_xor(s, 16);
            s += __shfl_xor(s, 32);
            sv4[b] = s;
        }
        float v = sv4[0];
        v = (g == 1) ? sv4[1] : v;
        v = (g == 2) ? sv4[2] : v;
        v = (g == 3) ? sv4[3] : v;

        const float vn = __shfl_xor(v, 1);
        if ((l & 1) == 0)
            partial32[(size_t)w * 32 + (l >> 1)] = pack_bf16(v, vn);
    }
    // drain all gloads before wave exit (LDS gets reallocated)
    asm volatile("s_waitcnt vmcnt(0)" ::: "memory");
}

// ---------------------------------------------------------------------------
// Reduce windows per node (2 nodes per wave): aggb[n] = bf16(sum partials).
// ---------------------------------------------------------------------------
__global__ __launch_bounds__(256) void k_red(const unsigned* __restrict__ partial32,
                                             const int* __restrict__ pstart,
                                             unsigned* __restrict__ aggb32) {
    const int l = threadIdx.x & 63;
    const int q = l & 31;
    int nb = (blockIdx.x * blockDim.x + threadIdx.x) >> 6;
    nb = __builtin_amdgcn_readfirstlane(nb);
    const int n = 2 * nb + (l >> 5);
    if (n >= NN) return;

    const int w0 = pstart[n] >> 4;
    const int w1 = pstart[n + 1] >> 4;
    float c0 = 0.0f, c1 = 0.0f;
    for (int w = w0; w < w1; ++w) {
        const unsigned uu = partial32[(size_t)w * 32 + q];
        c0 += __uint_as_float(uu << 16);
        c1 += __uint_as_float(uu & 0xffff0000u);
    }
    aggb32[(size_t)n * 32 + q] = pack_bf16(c0, c1);
}

// ---------------------------------------------------------------------------
// Node MLP via MFMA: out = relu([x_bf16 | agg_bf16] @ W2[0:128] + uW2b[batch])
// ---------------------------------------------------------------------------
__global__ __launch_bounds__(256) void k_nodem(const unsigned short* __restrict__ xb,
                                               const unsigned short* __restrict__ aggb,
                                               const int* __restrict__ bat,
                                               const float* __restrict__ uW2b,
                                               const float* __restrict__ W2,
                                               float* __restrict__ out) {
    const int l = threadIdx.x & 63;
    const int g = l >> 4;
    const int c = l & 15;

    short8 wf[4][4];
#pragma unroll
    for (int t = 0; t < 4; ++t)
#pragma unroll
        for (int b = 0; b < 4; ++b)
#pragma unroll
            for (int i = 0; i < 8; i += 2) {
                const int k = 32 * t + 8 * g + i;
                const unsigned p = pack_bf16(W2[k * OD + (c + 16 * b)],
                                             W2[(k + 1) * OD + (c + 16 * b)]);
                ((unsigned*)&wf[t][b])[i / 2] = p;
            }

    int wv = (blockIdx.x * blockDim.x + threadIdx.x) >> 6;
    wv = __builtin_amdgcn_readfirstlane(wv);

    for (int w = wv; w < NWIN_N; w += NODE_WAVES) {
        const int n0 = w * 16;
        const uint4* xr = (const uint4*)(xb + (size_t)(n0 + c) * FN);
        const uint4* ar = (const uint4*)(aggb + (size_t)(n0 + c) * OD);
        uint4 qx0 = xr[g], qx1 = xr[4 + g];
        uint4 qa0 = ar[g], qa1 = ar[4 + g];
        short8 a0 = *(short8*)&qx0, a1 = *(short8*)&qx1;
        short8 a2 = *(short8*)&qa0, a3 = *(short8*)&qa1;

        int bq[4];
#pragma unroll
        for (int q = 0; q < 4; ++q) bq[q] = bat[n0 + g * 4 + q];

#pragma unroll
        for (int b = 0; b < 4; ++b) {
            f32x4 acc = {0.f, 0.f, 0.f, 0.f};
            acc = __builtin_amdgcn_mfma_f32_16x16x32_bf16(a0, wf[0][b], acc, 0, 0, 0);
            acc = __builtin_amdgcn_mfma_f32_16x16x32_bf16(a1, wf[1][b], acc, 0, 0, 0);
            acc = __builtin_amdgcn_mfma_f32_16x16x32_bf16(a2, wf[2][b], acc, 0, 0, 0);
            acc = __builtin_amdgcn_mfma_f32_16x16x32_bf16(a3, wf[3][b], acc, 0, 0, 0);
#pragma unroll
            for (int q = 0; q < 4; ++q) {
                const int n = n0 + g * 4 + q;
                const float val = acc[q] + uW2b[(size_t)bq[q] * OD + c + 16 * b];
                out[(size_t)n * OD + c + 16 * b] = fmaxf(val, 0.0f);
            }
        }
    }
}

// ---------------------------------------------------------------------------
extern "C" void kernel_launch(void* const* d_in, const int* in_sizes, int n_in,
                              void* d_out, int out_size, void* d_ws, size_t ws_size,
                              hipStream_t stream) {
    const float* x    = (const float*)d_in[0];   // (50000, 64)
    const int*   ei   = (const int*)d_in[1];     // (2, 800000)
    const float* ea   = (const float*)d_in[2];   // (800000, 32)
    const float* u    = (const float*)d_in[3];   // (256, 32)
    const int*   bat  = (const int*)d_in[4];     // (50000,)
    const float* W1   = (const float*)d_in[5];   // (96, 64)
    const float* b1   = (const float*)d_in[6];   // (64,)
    const float* W2   = (const float*)d_in[7];   // (160, 64)
    const float* b2   = (const float*)d_in[8];   // (64,)
    float* out = (float*)d_out;                  // (50000, 64)

    // workspace layout (~39 MB)
    char* ws = (char*)d_ws;
    auto alloc = [&](size_t bytes) {
        char* p = ws;
        ws += (bytes + 255) & ~size_t(255);
        return p;
    };
    unsigned short* xb   = (unsigned short*)alloc((size_t)NN * FN * 2);    // 6.4 MB
    unsigned short* aggb = (unsigned short*)alloc((size_t)NN * OD * 2);    // 6.4 MB
    float* uW2b    = (float*)alloc((size_t)NG * OD * sizeof(float));
    int*   cnt     = (int*)alloc((size_t)NN * sizeof(int));
    int*   pstart  = (int*)alloc((size_t)(NN + 1) * sizeof(int));
    int*   cursor  = (int*)alloc((size_t)NN * sizeof(int));
    int*   bsum    = (int*)alloc((size_t)NBLK * sizeof(int));
    int*   winend  = (int*)alloc((size_t)NWIN_MAX * sizeof(int));          // 0.39 MB
    int2*  bucket  = (int2*)alloc((size_t)SLOTS_MAX * sizeof(int2));       // 12.4 MB
    unsigned* partial = (unsigned*)alloc((size_t)NWIN_MAX * 32 * 4);       // 12.4 MB

    // fused precompute (x->bf16, uW2b, zero cnt)
    k_pre<<<dim3(PRE_BLOCKS), dim3(256), 0, stream>>>(x, (unsigned*)xb, u, W2, b2, uW2b, cnt);

    // dst histogram + padded exclusive scan (+ per-window segment ends)
    k_hist<<<dim3((NE + 255) / 256), dim3(256), 0, stream>>>(ei, cnt);
    k_scan1<<<dim3(NBLK), dim3(SCAN_B), 0, stream>>>(cnt, pstart, bsum);
    k_scan23<<<dim3(NBLK), dim3(SCAN_B), 0, stream>>>(pstart, bsum, cnt, cursor, winend);

    // light scatter {src,e} into dst-sorted padded buckets
    k_scatter<<<dim3((NE + 255) / 256), dim3(256), 0, stream>>>(ei, cursor, bucket);

    // gather-window MFMA with global_load_lds ring pipeline
    k_aggw4<<<dim3(AGG4_BLOCKS), dim3(256), 0, stream>>>(bucket, ea, xb, W1, b1,
                                                         pstart, winend, partial);

    // per-node reduce of window partials
    k_red<<<dim3((NN * 32 + 255) / 256), dim3(256), 0, stream>>>(partial, pstart, (unsigned*)aggb);

    // node MLP (MFMA)
    k_nodem<<<dim3(NODE_BLOCKS), dim3(256), 0, stream>>>(xb, aggb, bat, uW2b, W2, out);
}

// Round 12
// 145.051 us; speedup vs baseline: 1.1865x; 1.1865x over previous
//
#include <hip/hip_runtime.h>
#include <hip/hip_bf16.h>
#include <hip/hip_fp16.h>

typedef __attribute__((ext_vector_type(8))) short short8;
typedef __attribute__((ext_vector_type(4))) float f32x4;

// Problem constants (from reference)
constexpr int NN = 50000;   // nodes
constexpr int NE = 800000;  // edges
constexpr int FN = 64;      // node feat
constexpr int FE = 32;      // edge feat
constexpr int FG = 32;      // global feat
constexpr int OD = 64;      // out dim
constexpr int NG = 256;     // graphs

constexpr int SCAN_B = 256;
constexpr int NBLK = (NN + SCAN_B - 1) / SCAN_B;        // 196

constexpr int NWIN_E = NE / 16;                         // 50000 edge windows
constexpr int MS_BLOCKS = 2048;
constexpr int MS_WAVES  = MS_BLOCKS * 4;

constexpr int XCVT_BLOCKS = (NN * FN / 8 + 255) / 256;  // 1563
constexpr int PRE_BLOCKS  = XCVT_BLOCKS + (NG * 64) / 256;

constexpr int NWIN_N = NN / 16;                         // 3125
constexpr int NODE_BLOCKS = 782;                        // 1 window per wave
constexpr int NODE_WAVES  = NODE_BLOCKS * 4;

static __device__ __forceinline__ unsigned pack_bf16(float a, float b) {
    __hip_bfloat162 h = __float22bfloat162_rn(float2{a, b});
    return *reinterpret_cast<unsigned*>(&h);
}

// ---------------------------------------------------------------------------
// Fused precompute: x->bf16 table, uW2b = b2 + u@W2_u (exact f32), zero cnt.
// ---------------------------------------------------------------------------
__global__ __launch_bounds__(256) void k_pre(const float* __restrict__ x,
                                             unsigned* __restrict__ xb32,
                                             const float* __restrict__ u,
                                             const float* __restrict__ W2,
                                             const float* __restrict__ b2,
                                             float* __restrict__ uW2b,
                                             int* __restrict__ cnt) {
    if (blockIdx.x >= XCVT_BLOCKS) {  // uW2b part
        const int lane = threadIdx.x & 63;
        float wcol[FG];
#pragma unroll
        for (int k = 0; k < FG; ++k) wcol[k] = W2[(FN + OD + k) * OD + lane];
        const float bias = b2[lane];
        int g = ((blockIdx.x - XCVT_BLOCKS) * 256 + threadIdx.x) >> 6;
        g = __builtin_amdgcn_readfirstlane(g);
        if (g >= NG) return;
        const float* __restrict__ urow = u + (size_t)g * FG;
        float acc = bias;
#pragma unroll
        for (int k = 0; k < FG; ++k) acc = fmaf(urow[k], wcol[k], acc);
        uW2b[(size_t)g * OD + lane] = acc;
        return;
    }
    const int i = blockIdx.x * 256 + threadIdx.x;
    if (i < NN) cnt[i] = 0;
    if (i >= NN * FN / 8) return;
    const float4* p = (const float4*)(x + (size_t)i * 8);
    float4 f0 = p[0], f1 = p[1];
    uint4 o;
    o.x = pack_bf16(f0.x, f0.y);
    o.y = pack_bf16(f0.z, f0.w);
    o.z = pack_bf16(f1.x, f1.y);
    o.w = pack_bf16(f1.z, f1.w);
    ((uint4*)xb32)[i] = o;
}

// ---------------------------------------------------------------------------
// Histogram of dst.
// ---------------------------------------------------------------------------
__global__ __launch_bounds__(256) void k_hist(const int* __restrict__ ei,
                                              int* __restrict__ cnt) {
    const int e = blockIdx.x * blockDim.x + threadIdx.x;
    if (e < NE) atomicAdd(&cnt[ei[e]], 1);
}

// ---------------------------------------------------------------------------
// Scan step 1 (unpadded counts): block-local exclusive + block sums.
// ---------------------------------------------------------------------------
__global__ __launch_bounds__(SCAN_B) void k_scan1(const int* __restrict__ cnt,
                                                  int* __restrict__ start,
                                                  int* __restrict__ bsum) {
    __shared__ int lds[SCAN_B];
    const int i = blockIdx.x * SCAN_B + threadIdx.x;
    const int v = (i < NN) ? cnt[i] : 0;
    lds[threadIdx.x] = v;
    __syncthreads();
#pragma unroll
    for (int off = 1; off < SCAN_B; off <<= 1) {
        int t = (threadIdx.x >= off) ? lds[threadIdx.x - off] : 0;
        __syncthreads();
        lds[threadIdx.x] += t;
        __syncthreads();
    }
    const int incl = lds[threadIdx.x];
    if (i < NN) start[i] = incl - v;  // exclusive within block
    if (threadIdx.x == SCAN_B - 1) bsum[blockIdx.x] = incl;
}

// ---------------------------------------------------------------------------
// Scan steps 2+3 fused: every block re-scans block sums in LDS, finalizes
// start/cursor; start[NN] = NE.
// ---------------------------------------------------------------------------
__global__ __launch_bounds__(SCAN_B) void k_scan23(int* __restrict__ start,
                                                   const int* __restrict__ bsum,
                                                   const int* __restrict__ cnt,
                                                   int* __restrict__ cursor) {
    __shared__ int lds[SCAN_B];
    const int t = threadIdx.x;
    lds[t] = (t < NBLK) ? bsum[t] : 0;
    __syncthreads();
#pragma unroll
    for (int off = 1; off < SCAN_B; off <<= 1) {
        int tv = (t >= off) ? lds[t - off] : 0;
        __syncthreads();
        lds[t] += tv;
        __syncthreads();
    }
    const int boff = (blockIdx.x == 0) ? 0 : lds[blockIdx.x - 1];

    const int i = blockIdx.x * SCAN_B + t;
    if (i < NN) {
        const int s = start[i] + boff;
        start[i] = s;
        cursor[i] = s;
        if (i == NN - 1) start[NN] = s + cnt[i];  // == NE
    }
}

// ---------------------------------------------------------------------------
// Edge-major message computation + scatter (r6 verbatim, the ONE permutation
// pass). All reads coalesced except the L2-resident xb table:
//   window = 16 consecutive edges; msg = relu([x_bf16[src] | ea] @ W1 + b1)
//   slot = atomic cursor[dst]; store msg row as f16 into mbuf[slot]
//   (column-permuted storage: f16 index slot*64 + c*4 + b holds col c+16b,
//    so each lane's 4 row-values are one contiguous 8 B store).
// Fragment layouts (mfma_f32_16x16x32_bf16), verified rounds 2-10:
//   A: row = lane&15, k = 8*(lane>>4)+i ; B: col = lane&15, same k
//   C: col = lane&15, row = (lane>>4)*4 + q
// ---------------------------------------------------------------------------
__global__ __launch_bounds__(256) void k_msgscat(const int* __restrict__ ei,
                                                 const float* __restrict__ ea,
                                                 const unsigned short* __restrict__ xb,
                                                 const float* __restrict__ W1,
                                                 const float* __restrict__ b1,
                                                 int* __restrict__ cursor,
                                                 unsigned short* __restrict__ mbuf) {
    const int l = threadIdx.x & 63;
    const int g = l >> 4;
    const int c = l & 15;

    // W1 B-fragments: wf[t][b] covers k = 32t.., cols 16b..16b+15
    short8 wf[3][4];
#pragma unroll
    for (int t = 0; t < 3; ++t)
#pragma unroll
        for (int b = 0; b < 4; ++b)
#pragma unroll
            for (int i = 0; i < 8; i += 2) {
                const int k = 32 * t + 8 * g + i;
                const unsigned p = pack_bf16(W1[k * OD + (c + 16 * b)],
                                             W1[(k + 1) * OD + (c + 16 * b)]);
                ((unsigned*)&wf[t][b])[i / 2] = p;
            }
    float bias[4];
#pragma unroll
    for (int b = 0; b < 4; ++b) bias[b] = b1[c + 16 * b];

    int wv = (blockIdx.x * blockDim.x + threadIdx.x) >> 6;
    wv = __builtin_amdgcn_readfirstlane(wv);

    for (int w = wv; w < NWIN_E; w += MS_WAVES) {
        const int e = w * 16 + c;            // this lane's edge (dup over g)
        const int dst = ei[e];               // coalesced
        const int src = ei[NE + e];          // coalesced
        int pos = 0;
        if (l < 16) pos = atomicAdd(&cursor[dst], 1);

        // A fragments: chunks 0,1 = x_bf16[src] (gather), chunk 2 = cvt(ea[e])
        short8 a0, a1, a2;
        {
            const uint4* xr = (const uint4*)(xb + (size_t)src * FN);
            uint4 q0 = xr[g];
            uint4 q1 = xr[4 + g];
            a0 = *(short8*)&q0;
            a1 = *(short8*)&q1;
        }
        {
            const float4* er = (const float4*)(ea + (size_t)e * FE);  // coalesced
            float4 e0 = er[2 * g], e1 = er[2 * g + 1];
            uint4 q2;
            q2.x = pack_bf16(e0.x, e0.y);
            q2.y = pack_bf16(e0.z, e0.w);
            q2.z = pack_bf16(e1.x, e1.y);
            q2.w = pack_bf16(e1.z, e1.w);
            a2 = *(short8*)&q2;
        }

        f32x4 accb[4];
#pragma unroll
        for (int b = 0; b < 4; ++b) {
            f32x4 acc = {0.f, 0.f, 0.f, 0.f};
            acc = __builtin_amdgcn_mfma_f32_16x16x32_bf16(a0, wf[0][b], acc, 0, 0, 0);
            acc = __builtin_amdgcn_mfma_f32_16x16x32_bf16(a1, wf[1][b], acc, 0, 0, 0);
            acc = __builtin_amdgcn_mfma_f32_16x16x32_bf16(a2, wf[2][b], acc, 0, 0, 0);
            accb[b] = acc;
        }

        // store: row r = 4g+q belongs to edge w*16+r; its slot came from lane r
#pragma unroll
        for (int q = 0; q < 4; ++q) {
            const int pr = __shfl(pos, 4 * g + q);  // slot of edge 4g+q
            const float v0 = fmaxf(accb[0][q] + bias[0], 0.0f);
            const float v1 = fmaxf(accb[1][q] + bias[1], 0.0f);
            const float v2 = fmaxf(accb[2][q] + bias[2], 0.0f);
            const float v3 = fmaxf(accb[3][q] + bias[3], 0.0f);
            const __half2 h01 = __float22half2_rn(float2{v0, v1});
            const __half2 h23 = __float22half2_rn(float2{v2, v3});
            uint2 outv;
            outv.x = *reinterpret_cast<const unsigned*>(&h01);
            outv.y = *reinterpret_cast<const unsigned*>(&h23);
            *reinterpret_cast<uint2*>(mbuf + (size_t)pr * 64 + c * 4) = outv;
        }
    }
}

// ---------------------------------------------------------------------------
// Fused segment-reduce + node MLP:
//   wave owns 16 consecutive nodes. Lane (g,c) sums node (n0+c)'s mbuf rows
//   (dst-sorted contiguous segment) over STORED chunks s=8g..8g+7 (a2) and
//   s=32+8g.. (a3) — contiguous uint4 reads, f32 accumulate — then packs to
//   bf16 A-fragments and runs the node MFMA with W2 rows permuted to match
//   the storage order (r7-verified wf build): stored s -> true col
//   (s>>2) + 16*(s&3).
//   out = relu([x_bf16 | agg] @ W2[0:128] + uW2b[batch])
// ---------------------------------------------------------------------------
__global__ __launch_bounds__(256) void k_nodem2(const unsigned short* __restrict__ xb,
                                                const unsigned short* __restrict__ mbuf,
                                                const int* __restrict__ start,
                                                const int* __restrict__ bat,
                                                const float* __restrict__ uW2b,
                                                const float* __restrict__ W2,
                                                float* __restrict__ out) {
    const int l = threadIdx.x & 63;
    const int g = l >> 4;
    const int c = l & 15;

    // W2 B-fragments; t>=2 rows permuted to storage order (verified r7)
    short8 wf[4][4];
#pragma unroll
    for (int t = 0; t < 4; ++t)
#pragma unroll
        for (int b = 0; b < 4; ++b)
#pragma unroll
            for (int i = 0; i < 8; i += 2) {
                const int col = c + 16 * b;
                unsigned p;
                if (t < 2) {
                    const int k = 32 * t + 8 * g + i;
                    p = pack_bf16(W2[k * OD + col], W2[(k + 1) * OD + col]);
                } else {
                    const int sc0 = 32 * (t - 2) + 8 * g + i;
                    const int sc1 = sc0 + 1;
                    const int k0 = FN + ((sc0 >> 2) + 16 * (sc0 & 3));
                    const int k1 = FN + ((sc1 >> 2) + 16 * (sc1 & 3));
                    p = pack_bf16(W2[k0 * OD + col], W2[k1 * OD + col]);
                }
                ((unsigned*)&wf[t][b])[i / 2] = p;
            }

    int wv = (blockIdx.x * blockDim.x + threadIdx.x) >> 6;
    wv = __builtin_amdgcn_readfirstlane(wv);

    for (int w = wv; w < NWIN_N; w += NODE_WAVES) {
        const int n0 = w * 16;
        const int n = n0 + c;
        const int s0 = start[n];
        const int cntn = start[n + 1] - s0;

        // wave-max segment length over the 16 nodes (g-groups share c-set)
        int mc = cntn;
        mc = max(mc, __shfl_xor(mc, 1));
        mc = max(mc, __shfl_xor(mc, 2));
        mc = max(mc, __shfl_xor(mc, 4));
        mc = max(mc, __shfl_xor(mc, 8));

        // segment sum in f32, stored-order chunks
        float s2v[8] = {0, 0, 0, 0, 0, 0, 0, 0};
        float s3v[8] = {0, 0, 0, 0, 0, 0, 0, 0};
        const unsigned short* rowb = mbuf + (size_t)s0 * 64 + 8 * g;
        for (int i = 0; i < mc; ++i) {
            if (i < cntn) {
                const uint4 u2 = *(const uint4*)(rowb + (size_t)i * 64);
                const uint4 u3 = *(const uint4*)(rowb + (size_t)i * 64 + 32);
                const __half2* h2 = (const __half2*)&u2;
                const __half2* h3 = (const __half2*)&u3;
#pragma unroll
                for (int j = 0; j < 4; ++j) {
                    const float2 f2 = __half22float2(h2[j]);
                    const float2 f3 = __half22float2(h3[j]);
                    s2v[2 * j]     += f2.x;
                    s2v[2 * j + 1] += f2.y;
                    s3v[2 * j]     += f3.x;
                    s3v[2 * j + 1] += f3.y;
                }
            }
        }
        uint4 qa2, qa3;
        qa2.x = pack_bf16(s2v[0], s2v[1]);
        qa2.y = pack_bf16(s2v[2], s2v[3]);
        qa2.z = pack_bf16(s2v[4], s2v[5]);
        qa2.w = pack_bf16(s2v[6], s2v[7]);
        qa3.x = pack_bf16(s3v[0], s3v[1]);
        qa3.y = pack_bf16(s3v[2], s3v[3]);
        qa3.z = pack_bf16(s3v[4], s3v[5]);
        qa3.w = pack_bf16(s3v[6], s3v[7]);

        // x A-fragments (coalesced: consecutive node rows)
        const uint4* xr = (const uint4*)(xb + (size_t)n * FN);
        uint4 qx0 = xr[g], qx1 = xr[4 + g];
        short8 a0 = *(short8*)&qx0, a1 = *(short8*)&qx1;
        short8 a2 = *(short8*)&qa2, a3 = *(short8*)&qa3;

        int bq[4];
#pragma unroll
        for (int q = 0; q < 4; ++q) bq[q] = bat[n0 + g * 4 + q];

#pragma unroll
        for (int b = 0; b < 4; ++b) {
            f32x4 acc = {0.f, 0.f, 0.f, 0.f};
            acc = __builtin_amdgcn_mfma_f32_16x16x32_bf16(a0, wf[0][b], acc, 0, 0, 0);
            acc = __builtin_amdgcn_mfma_f32_16x16x32_bf16(a1, wf[1][b], acc, 0, 0, 0);
            acc = __builtin_amdgcn_mfma_f32_16x16x32_bf16(a2, wf[2][b], acc, 0, 0, 0);
            acc = __builtin_amdgcn_mfma_f32_16x16x32_bf16(a3, wf[3][b], acc, 0, 0, 0);
#pragma unroll
            for (int q = 0; q < 4; ++q) {
                const int nn = n0 + g * 4 + q;
                const float val = acc[q] + uW2b[(size_t)bq[q] * OD + c + 16 * b];
                out[(size_t)nn * OD + c + 16 * b] = fmaxf(val, 0.0f);
            }
        }
    }
}

// ---------------------------------------------------------------------------
extern "C" void kernel_launch(void* const* d_in, const int* in_sizes, int n_in,
                              void* d_out, int out_size, void* d_ws, size_t ws_size,
                              hipStream_t stream) {
    const float* x    = (const float*)d_in[0];   // (50000, 64)
    const int*   ei   = (const int*)d_in[1];     // (2, 800000)
    const float* ea   = (const float*)d_in[2];   // (800000, 32)
    const float* u    = (const float*)d_in[3];   // (256, 32)
    const int*   bat  = (const int*)d_in[4];     // (50000,)
    const float* W1   = (const float*)d_in[5];   // (96, 64)
    const float* b1   = (const float*)d_in[6];   // (64,)
    const float* W2   = (const float*)d_in[7];   // (160, 64)
    const float* b2   = (const float*)d_in[8];   // (64,)
    float* out = (float*)d_out;                  // (50000, 64)

    // workspace layout (~110 MB; mbuf dominates)
    char* ws = (char*)d_ws;
    auto alloc = [&](size_t bytes) {
        char* p = ws;
        ws += (bytes + 255) & ~size_t(255);
        return p;
    };
    unsigned short* xb = (unsigned short*)alloc((size_t)NN * FN * 2);     // 6.4 MB
    float* uW2b    = (float*)alloc((size_t)NG * OD * sizeof(float));
    int*   cnt     = (int*)alloc((size_t)NN * sizeof(int));
    int*   start   = (int*)alloc((size_t)(NN + 1) * sizeof(int));
    int*   cursor  = (int*)alloc((size_t)NN * sizeof(int));
    int*   bsum    = (int*)alloc((size_t)NBLK * sizeof(int));
    unsigned short* mbuf = (unsigned short*)alloc((size_t)NE * OD * 2);   // 102.4 MB

    // fused precompute (x->bf16, uW2b, zero cnt)
    k_pre<<<dim3(PRE_BLOCKS), dim3(256), 0, stream>>>(x, (unsigned*)xb, u, W2, b2, uW2b, cnt);

    // dst histogram + exclusive scan
    k_hist<<<dim3((NE + 255) / 256), dim3(256), 0, stream>>>(ei, cnt);
    k_scan1<<<dim3(NBLK), dim3(SCAN_B), 0, stream>>>(cnt, start, bsum);
    k_scan23<<<dim3(NBLK), dim3(SCAN_B), 0, stream>>>(start, bsum, cnt, cursor);

    // the one permutation pass: edge-major MFMA messages -> dst-sorted slots
    k_msgscat<<<dim3(MS_BLOCKS), dim3(256), 0, stream>>>(ei, ea, xb, W1, b1, cursor, mbuf);

    // fused segment-reduce + node MLP
    k_nodem2<<<dim3(NODE_BLOCKS), dim3(256), 0, stream>>>(xb, mbuf, start, bat, uW2b, W2, out);
}